// Round 5
// baseline (315.301 us; speedup 1.0000x reference)
//
#include <hip/hip_runtime.h>
#include <hip/hip_bf16.h>
#include <cstdint>

// ---------------------------------------------------------------------------
// LinearMultiHeadAttention: B=4, S=4096, D_MODEL=1024, H=16, Dk=64
// Gram-path:
//   G[b]  = x[b]^T x[b]     (SYMMETRIC: upper-triangle tiles only, split-K=4)
//   H[b]  = Wk @ G[b]
//   kv[b,h] = H_h @ Wv_h^T
//   E_t[b][j][hd] = scale*sum_e kv*Wo
//   F[b]  = E_t[b] @ Wq
//   out   = x @ F[b]^T
// R11 vs R10:
//   - gemm_gram3 REVERTED to R8's gemm_gram (2-barrier, 56 VGPR): the
//     launch_bounds(256,3) variant capped VGPR at ~84 -> spill; cost ~+14us.
//   - gemm_fin: split lgkm waits. Issue bf(4)+af0-3(4)+af4-7(4) ds_reads,
//     wait lgkmcnt(4) (bf+af0-3 certified), 16 MFMA overlap af4-7 drain,
//     lgkmcnt(0), 16 MFMA. sched_barrier(0) pins group order (rule #18).
//     + XCD-bijective blockIdx remap (512=8x64: each XCD chunk shares z and
//     4 B-panels -> B refetched once per XCD, in-loop loads L2-local).
//     Ledger unchanged (3-buf, stage kt+2, vmcnt(6) checkpoint, 1 BAR/kt).
// ---------------------------------------------------------------------------

typedef __bf16 bf16x8 __attribute__((ext_vector_type(8)));
typedef float f32x4 __attribute__((ext_vector_type(4)));
typedef unsigned short ushort_t;

__device__ inline void gld_lds16(const void* g, void* l) {
    __builtin_amdgcn_global_load_lds(
        (const __attribute__((address_space(1))) unsigned int*)g,
        (__attribute__((address_space(3))) unsigned int*)l,
        16, 0, 0);
}

__device__ inline ushort_t f2bf(float f) {
    uint32_t u = __float_as_uint(f);
    uint32_t r = (u + 0x7fffu + ((u >> 16) & 1u)) >> 16;
    return (ushort_t)r;
}
__device__ inline float bf2f(ushort_t u) {
    return __uint_as_float((uint32_t)u << 16);
}

// ---------------------------------------------------------------------------
// C = A @ B^T. 128x64 tile, BK=32, XOR-swizzled LDS. 256 thr = 4 waves (2Mx2N),
// per-wave 64x32 out. 512 blocks for 1024x1024 GEMMs -> 2/CU resident.
// ---------------------------------------------------------------------------
template <typename OutT>
__global__ __launch_bounds__(256, 4)
void gemm_bt_n64(const ushort_t* __restrict__ A, int lda, long strideA,
                 const ushort_t* __restrict__ B, int ldb, long strideB,
                 OutT* __restrict__ C0, int ldc0, long strideC0, int K)
{
    __shared__ ushort_t lA[128 * 32];
    __shared__ ushort_t lB[64 * 32];

    const int t    = threadIdx.x;
    const int lane = t & 63;
    const int wid  = t >> 6;          // 0..3
    const int z    = blockIdx.z;

    A += (size_t)z * strideA;
    B += (size_t)z * strideB;

    const int m0 = blockIdx.x * 128;
    const int n0 = blockIdx.y * 64;

    const int wm = (wid >> 1) * 64;   // 0,64
    const int wn = (wid & 1) * 32;    // 0,32
    const int mr = lane & 15;
    const int q4 = lane >> 4;

    const int row_a = t >> 2;                       // 0..63
    const int seg   = ((t & 3) ^ ((t >> 3) & 3)) * 8;
    const int csw   = (q4 ^ ((mr >> 1) & 3)) * 16;

    f32x4 acc[4][2] = {};

    for (int k0 = 0; k0 < K; k0 += 32) {
        __syncthreads();
        gld_lds16(A + (size_t)(m0 + row_a) * lda + k0 + seg,      (char*)lA + wid * 1024);
        gld_lds16(A + (size_t)(m0 + 64 + row_a) * lda + k0 + seg, (char*)lA + 4096 + wid * 1024);
        gld_lds16(B + (size_t)(n0 + row_a) * ldb + k0 + seg,      (char*)lB + wid * 1024);
        __syncthreads();

        bf16x8 af[4], bf[2];
#pragma unroll
        for (int i = 0; i < 4; ++i)
            af[i] = *(const bf16x8*)((const char*)lA + (wm + i * 16 + mr) * 64 + csw);
#pragma unroll
        for (int j = 0; j < 2; ++j)
            bf[j] = *(const bf16x8*)((const char*)lB + (wn + j * 16 + mr) * 64 + csw);
#pragma unroll
        for (int i = 0; i < 4; ++i)
#pragma unroll
            for (int j = 0; j < 2; ++j)
                acc[i][j] = __builtin_amdgcn_mfma_f32_16x16x32_bf16(af[i], bf[j], acc[i][j], 0, 0, 0);
    }

    OutT* Cw = C0 + (size_t)z * strideC0;
#pragma unroll
    for (int i = 0; i < 4; ++i) {
        const int rbase = m0 + wm + i * 16 + q4 * 4;
#pragma unroll
        for (int j = 0; j < 2; ++j) {
            const int col = n0 + wn + j * 16 + mr;
#pragma unroll
            for (int r = 0; r < 4; ++r) {
                const float v = acc[i][j][r];
                const size_t off = (size_t)(rbase + r) * ldc0 + col;
                if constexpr (sizeof(OutT) == 2) Cw[off] = f2bf(v);
                else                             Cw[off] = v;
            }
        }
    }
}

// ---------------------------------------------------------------------------
// FINAL GEMM: C = A @ B^T fp32. 256x128 tile, BK=32, 4 waves, wave = 128x64
// (acc[8][4], 32 MFMA / 12 ds_read). TRIPLE-buffered LDS (3x24KB=72KB) ->
// 2 blocks/CU. One s_barrier per kt, counted-vmcnt ledger (see R10 comment).
// R11: split lgkm waits -- bf+af0-3 at lgkmcnt(4), MFMA half 1 overlaps
// af4-7 drain, lgkmcnt(0), MFMA half 2. XCD-bijective blockIdx remap.
// ---------------------------------------------------------------------------
__global__ __launch_bounds__(256, 2)
void gemm_fin(const ushort_t* __restrict__ A, int lda, long strideA,
              const ushort_t* __restrict__ B, int ldb, long strideB,
              float* __restrict__ C, int ldc, long strideC, int K)
{
    __shared__ char lds[73728];      // 3 x 24576 (A@0..16K, B@16K..24K)

    const int t    = threadIdx.x;    // 256
    const int lane = t & 63;
    const int wid  = t >> 6;         // 0..3

    // XCD-bijective remap: 512 blocks = 8 XCD chunks of 64. Chunk c (= XCD)
    // covers z = c/2, by in {4(c&1)..4(c&1)+3}, all bx -> B panels (1MB) and
    // the z-slice are XCD-L2-resident; A panels reused 4x within chunk.
    const int L  = blockIdx.x + (blockIdx.y << 4) + (blockIdx.z << 7);
    const int w  = ((L & 7) << 6) + (L >> 3);
    const int bx = w & 15, by = (w >> 4) & 7, z = w >> 7;

    A += (size_t)z * strideA;
    B += (size_t)z * strideB;

    const int m0 = bx * 256;
    const int n0 = by * 128;

    const int wr = wid >> 1;         // 0..1: 128-row half of A-tile
    const int wn = wid & 1;          // 0..1: 64-col half of B-tile
    const int mr = lane & 15;
    const int q4 = lane >> 4;

    const int NT = K >> 5;           // 32

    const int row_a = t >> 2;                         // 0..63
    const int seg   = ((t & 3) ^ ((t >> 3) & 3)) * 8; // inverse-swizzled src col
    const int csw   = (q4 ^ ((mr >> 1) & 3)) * 16;    // swizzled read col

    auto stage = [&](int tgt, int bsel) {
        if (tgt >= NT) return;
        char* base = lds + bsel * 24576 + wid * 1024;
        const ushort_t* gA = A + (size_t)(m0 + row_a) * lda + tgt * 32 + seg;
        gld_lds16(gA,                          base);          // rows   0..63
        gld_lds16(gA + ((size_t)lda << 6),     base + 4096);   // rows  64..127
        gld_lds16(gA + ((size_t)lda << 7),     base + 8192);   // rows 128..191
        gld_lds16(gA + (size_t)lda * 192,      base + 12288);  // rows 192..255
        const ushort_t* gB = B + (size_t)(n0 + row_a) * ldb + tgt * 32 + seg;
        gld_lds16(gB,                          base + 16384);  // rows   0..63
        gld_lds16(gB + ((size_t)ldb << 6),     base + 20480);  // rows  64..127
    };

    bf16x8 af[8], bf[4];
    f32x4 acc[8][4] = {};

#define SB() __builtin_amdgcn_sched_barrier(0)

    // prologue
    stage(0, 0);
    stage(1, 1);
    asm volatile("s_waitcnt vmcnt(6)" ::: "memory");
    __builtin_amdgcn_s_barrier();

    int cur = 0;
    for (int kt = 0; kt < NT; ++kt) {
        const char* buf = lds + cur * 24576;
        int b2 = cur + 2; if (b2 >= 3) b2 -= 3;
        stage(kt + 2, b2);
        SB();
        // --- pinned read groups: bf(4) | af0-3(4) | af4-7(4) ---
#pragma unroll
        for (int j = 0; j < 4; ++j)
            bf[j] = *(const bf16x8*)(buf + 16384 + (wn * 64 + j * 16 + mr) * 64 + csw);
        SB();
#pragma unroll
        for (int i = 0; i < 4; ++i)
            af[i] = *(const bf16x8*)(buf + (wr * 128 + i * 16 + mr) * 64 + csw);
        SB();
#pragma unroll
        for (int i = 4; i < 8; ++i)
            af[i] = *(const bf16x8*)(buf + (wr * 128 + i * 16 + mr) * 64 + csw);
        SB();

        asm volatile("s_waitcnt lgkmcnt(4)" ::: "memory");   // bf + af0-3 done
        SB();
        __builtin_amdgcn_s_setprio(1);
#pragma unroll
        for (int i = 0; i < 4; ++i)
#pragma unroll
            for (int j = 0; j < 4; ++j)
                acc[i][j] = __builtin_amdgcn_mfma_f32_16x16x32_bf16(
                    af[i], bf[j], acc[i][j], 0, 0, 0);
        __builtin_amdgcn_s_setprio(0);
        SB();
        asm volatile("s_waitcnt lgkmcnt(0)" ::: "memory");   // af4-7 done
        SB();
        __builtin_amdgcn_s_setprio(1);
#pragma unroll
        for (int i = 4; i < 8; ++i)
#pragma unroll
            for (int j = 0; j < 4; ++j)
                acc[i][j] = __builtin_amdgcn_mfma_f32_16x16x32_bf16(
                    af[i], bf[j], acc[i][j], 0, 0, 0);
        __builtin_amdgcn_s_setprio(0);
        SB();

        if (kt + 2 < NT)       asm volatile("s_waitcnt vmcnt(6)" ::: "memory");
        else if (kt + 2 == NT) asm volatile("s_waitcnt vmcnt(0)" ::: "memory");
        __builtin_amdgcn_s_barrier();
        if (++cur == 3) cur = 0;
    }

#undef SB

    float* Cw = C + (size_t)z * strideC;
#pragma unroll
    for (int i = 0; i < 8; ++i) {
        const int rbase = m0 + wr * 128 + i * 16 + q4 * 4;
#pragma unroll
        for (int j = 0; j < 4; ++j) {
            const int col = n0 + wn * 64 + j * 16 + mr;
#pragma unroll
            for (int r = 0; r < 4; ++r)
                Cw[(size_t)(rbase + r) * ldc + col] = acc[i][j][r];
        }
    }
}

// ---------------------------------------------------------------------------
// Gram GEMM (reverted to R8 version): Gp[z] partial of x[b]^T x[b],
// upper-triangle 128-tiles only. grid (16 z fastest -> XCD round-robin,
// 36 triangle tiles). A = B = xbT. z = b*4+ks.
// ---------------------------------------------------------------------------
__global__ __launch_bounds__(256, 2)
void gemm_gram(const ushort_t* __restrict__ X, ushort_t* __restrict__ Gp)
{
    __shared__ ushort_t lA[128 * 32];
    __shared__ ushort_t lB[128 * 32];

    const int t    = threadIdx.x;
    const int lane = t & 63;
    const int wid  = t >> 6;

    const int z  = blockIdx.x;
    const int bb = z >> 2, ks = z & 3;

    // triangle tile map: row ti has 8-ti tiles (ti<=tj)
    int ti = 0, rem = blockIdx.y;
    while (rem >= 8 - ti) { rem -= 8 - ti; ++ti; }
    const int tj = ti + rem;
    const int m0 = ti * 128;
    const int n0 = tj * 128;

    const ushort_t* A = X + (size_t)bb * 4096 + (size_t)ks * 1024;

    const int wm = (wid >> 1) * 64;
    const int wn = (wid & 1) * 64;
    const int mr = lane & 15;
    const int q4 = lane >> 4;

    const int row_a = t >> 2;
    const int seg   = ((t & 3) ^ ((t >> 3) & 3)) * 8;
    const int csw   = (q4 ^ ((mr >> 1) & 3)) * 16;

    f32x4 acc[4][4] = {};

    for (int k0 = 0; k0 < 1024; k0 += 32) {
        __syncthreads();
        gld_lds16(A + (size_t)(m0 + row_a) * 16384 + k0 + seg,      (char*)lA + wid * 1024);
        gld_lds16(A + (size_t)(m0 + 64 + row_a) * 16384 + k0 + seg, (char*)lA + 4096 + wid * 1024);
        gld_lds16(A + (size_t)(n0 + row_a) * 16384 + k0 + seg,      (char*)lB + wid * 1024);
        gld_lds16(A + (size_t)(n0 + 64 + row_a) * 16384 + k0 + seg, (char*)lB + 4096 + wid * 1024);
        __syncthreads();

        bf16x8 af[4], bf[4];
#pragma unroll
        for (int i = 0; i < 4; ++i)
            af[i] = *(const bf16x8*)((const char*)lA + (wm + i * 16 + mr) * 64 + csw);
#pragma unroll
        for (int j = 0; j < 4; ++j)
            bf[j] = *(const bf16x8*)((const char*)lB + (wn + j * 16 + mr) * 64 + csw);
#pragma unroll
        for (int i = 0; i < 4; ++i)
#pragma unroll
            for (int j = 0; j < 4; ++j)
                acc[i][j] = __builtin_amdgcn_mfma_f32_16x16x32_bf16(af[i], bf[j], acc[i][j], 0, 0, 0);
    }

    ushort_t* Cw = Gp + ((size_t)z << 20);
#pragma unroll
    for (int i = 0; i < 4; ++i) {
        const int rbase = m0 + wm + i * 16 + q4 * 4;
#pragma unroll
        for (int j = 0; j < 4; ++j) {
            const int col = n0 + wn + j * 16 + mr;
#pragma unroll
            for (int r = 0; r < 4; ++r)
                Cw[(size_t)(rbase + r) * 1024 + col] = f2bf(acc[i][j][r]);
        }
    }
}

// ---------------------------------------------------------------------------
// reduce_g_t: G[b][tr*64+r][tc*64+c] = sum_ks Gp[b*4+ks] at source 64-tile
// (sr,sc)=(min,max). Lower tiles transpose through LDS (pitch 65).
// ---------------------------------------------------------------------------
__global__ __launch_bounds__(256)
void reduce_g_t(const ushort_t* __restrict__ Gp, ushort_t* __restrict__ G)
{
    __shared__ float acc[64 * 65];

    const int t  = threadIdx.x;
    const int b  = blockIdx.y;
    const int tr = blockIdx.x >> 4, tc = blockIdx.x & 15;
    const int sr = (tr <= tc) ? tr : tc;
    const int sc = (tr <= tc) ? tc : tr;
    const bool flip = tr > tc;

#pragma unroll
    for (int p = 0; p < 4; ++p) {
        const int idx = p * 256 + t;
        const int r = idx >> 4, c = (idx & 15) * 4;
        float a0 = 0.f, a1 = 0.f, a2 = 0.f, a3 = 0.f;
#pragma unroll
        for (int ksl = 0; ksl < 4; ++ksl) {
            const ushort4 u = *(const ushort4*)&Gp[((size_t)(b * 4 + ksl) << 20)
                                                   + (size_t)(sr * 64 + r) * 1024 + sc * 64 + c];
            a0 += bf2f(u.x); a1 += bf2f(u.y); a2 += bf2f(u.z); a3 += bf2f(u.w);
        }
        acc[r * 65 + c + 0] = a0;
        acc[r * 65 + c + 1] = a1;
        acc[r * 65 + c + 2] = a2;
        acc[r * 65 + c + 3] = a3;
    }
    __syncthreads();

#pragma unroll
    for (int p = 0; p < 4; ++p) {
        const int idx = p * 256 + t;
        const int r = idx >> 4, c = (idx & 15) * 4;
        float v0, v1, v2, v3;
        if (flip) {
            v0 = acc[(c + 0) * 65 + r];
            v1 = acc[(c + 1) * 65 + r];
            v2 = acc[(c + 2) * 65 + r];
            v3 = acc[(c + 3) * 65 + r];
        } else {
            v0 = acc[r * 65 + c + 0];
            v1 = acc[r * 65 + c + 1];
            v2 = acc[r * 65 + c + 2];
            v3 = acc[r * 65 + c + 3];
        }
        ushort4 o;
        o.x = f2bf(v0); o.y = f2bf(v1); o.z = f2bf(v2); o.w = f2bf(v3);
        *(ushort4*)&G[((size_t)b << 20) + (size_t)(tr * 64 + r) * 1024 + tc * 64 + c] = o;
    }
}

// ---------------------------------------------------------------------------
// cast x fp32 [16384][1024] -> xb bf16 + xbT bf16 [1024][16384]
// ---------------------------------------------------------------------------
__global__ __launch_bounds__(256)
void cast_x_t(const float* __restrict__ x, ushort_t* __restrict__ xb,
              ushort_t* __restrict__ xbT)
{
    __shared__ ushort_t lt[64 * 66];
    const int t  = threadIdx.x;
    const int s0 = blockIdx.x * 64;
    const int i0 = blockIdx.y * 64;

#pragma unroll
    for (int c = 0; c < 4; ++c) {
        const int idx = c * 256 + t;
        const int r = idx >> 4, c4 = (idx & 15) * 4;
        const float4 f = *(const float4*)&x[(size_t)(s0 + r) * 1024 + i0 + c4];
        ushort4 o;
        o.x = f2bf(f.x); o.y = f2bf(f.y); o.z = f2bf(f.z); o.w = f2bf(f.w);
        *(ushort4*)&xb[(size_t)(s0 + r) * 1024 + i0 + c4] = o;
        *(uint32_t*)&lt[r * 66 + c4]     = (uint32_t)o.x | ((uint32_t)o.y << 16);
        *(uint32_t*)&lt[r * 66 + c4 + 2] = (uint32_t)o.z | ((uint32_t)o.w << 16);
    }
    __syncthreads();
#pragma unroll
    for (int c = 0; c < 4; ++c) {
        const int idx = c * 256 + t;
        const int ri = idx >> 4, s4 = (idx & 15) * 4;
        ushort4 o;
        o.x = lt[(s4 + 0) * 66 + ri];
        o.y = lt[(s4 + 1) * 66 + ri];
        o.z = lt[(s4 + 2) * 66 + ri];
        o.w = lt[(s4 + 3) * 66 + ri];
        *(ushort4*)&xbT[(size_t)(i0 + ri) * 16384 + s0 + s4] = o;
    }
}

// ---------------------------------------------------------------------------
// cast+transpose Wq fp32 -> wqT bf16
// ---------------------------------------------------------------------------
__global__ __launch_bounds__(256)
void cast_wt(const float* __restrict__ W, ushort_t* __restrict__ WT)
{
    __shared__ ushort_t lt[64 * 66];
    const int t  = threadIdx.x;
    const int r0 = blockIdx.x * 64;
    const int c0 = blockIdx.y * 64;

#pragma unroll
    for (int c = 0; c < 4; ++c) {
        const int idx = c * 256 + t;
        const int r = idx >> 4, c4 = (idx & 15) * 4;
        const float4 f = *(const float4*)&W[(size_t)(r0 + r) * 1024 + c0 + c4];
        ushort4 o;
        o.x = f2bf(f.x); o.y = f2bf(f.y); o.z = f2bf(f.z); o.w = f2bf(f.w);
        *(uint32_t*)&lt[r * 66 + c4]     = (uint32_t)o.x | ((uint32_t)o.y << 16);
        *(uint32_t*)&lt[r * 66 + c4 + 2] = (uint32_t)o.z | ((uint32_t)o.w << 16);
    }
    __syncthreads();
#pragma unroll
    for (int c = 0; c < 4; ++c) {
        const int idx = c * 256 + t;
        const int ri = idx >> 4, s4 = (idx & 15) * 4;
        ushort4 o;
        o.x = lt[(s4 + 0) * 66 + ri];
        o.y = lt[(s4 + 1) * 66 + ri];
        o.z = lt[(s4 + 2) * 66 + ri];
        o.w = lt[(s4 + 3) * 66 + ri];
        *(ushort4*)&WT[(size_t)(c0 + ri) * 1024 + r0 + s4] = o;
    }
}

// ---------------------------------------------------------------------------
// plain cast Wk/Wv fp32 -> bf16
// ---------------------------------------------------------------------------
__global__ __launch_bounds__(256)
void cast_w2(const float* __restrict__ a, const float* __restrict__ b,
             ushort_t* __restrict__ out)
{
    const float* src = (blockIdx.y == 0) ? a : b;
    const int i = (blockIdx.x * 256 + threadIdx.x) * 4;
    const float4 f = *(const float4*)&src[i];
    ushort4 o;
    o.x = f2bf(f.x); o.y = f2bf(f.y); o.z = f2bf(f.z); o.w = f2bf(f.w);
    *(ushort4*)&out[(size_t)blockIdx.y * 1048576 + i] = o;
}

// ---------------------------------------------------------------------------
// kv partials: KVp[is][bh][d][e] = sum_{i-slice} H[b][h64+d][i]*Wv[h64+e][i]
// ---------------------------------------------------------------------------
__global__ __launch_bounds__(256)
void kvblk(const ushort_t* __restrict__ H, const ushort_t* __restrict__ Wv,
           float* __restrict__ KVp)
{
    __shared__ ushort_t sH[64 * 132];
    __shared__ ushort_t sV[64 * 132];

    const int t  = threadIdx.x;
    const int is = blockIdx.x;
    const int bh = blockIdx.y;
    const int b  = bh >> 4, h = bh & 15;

    const ushort_t* Hp = H + ((size_t)b << 20) + (size_t)(h * 64) * 1024 + is * 128;
    const ushort_t* Vp = Wv + (size_t)(h * 64) * 1024 + is * 128;

#pragma unroll
    for (int i2 = 0; i2 < 8; ++i2) {
        const int ci = i2 * 256 + t;
        const int r = ci >> 5, c = (ci & 31) * 4;
        *(uint2*)&sH[r * 132 + c] = *(const uint2*)&Hp[(size_t)r * 1024 + c];
        *(uint2*)&sV[r * 132 + c] = *(const uint2*)&Vp[(size_t)r * 1024 + c];
    }
    __syncthreads();

    const int d0 = (t >> 4) * 4;
    const int e0 = (t & 15) * 4;
    float acc[4][4] = {};

#pragma unroll 2
    for (int i4 = 0; i4 < 128; i4 += 4) {
        uint2 hu[4], vu[4];
#pragma unroll
        for (int j = 0; j < 4; ++j) {
            hu[j] = *(const uint2*)&sH[(d0 + j) * 132 + i4];
            vu[j] = *(const uint2*)&sV[(e0 + j) * 132 + i4];
        }
        float hf[4][4], vf[4][4];
#pragma unroll
        for (int j = 0; j < 4; ++j) {
            hf[j][0] = __uint_as_float(hu[j].x << 16);
            hf[j][1] = __uint_as_float(hu[j].x & 0xffff0000u);
            hf[j][2] = __uint_as_float(hu[j].y << 16);
            hf[j][3] = __uint_as_float(hu[j].y & 0xffff0000u);
            vf[j][0] = __uint_as_float(vu[j].x << 16);
            vf[j][1] = __uint_as_float(vu[j].x & 0xffff0000u);
            vf[j][2] = __uint_as_float(vu[j].y << 16);
            vf[j][3] = __uint_as_float(vu[j].y & 0xffff0000u);
        }
#pragma unroll
        for (int ii = 0; ii < 4; ++ii)
#pragma unroll
            for (int di = 0; di < 4; ++di)
#pragma unroll
                for (int ej = 0; ej < 4; ++ej)
                    acc[di][ej] += hf[di][ii] * vf[ej][ii];
    }

    float* outp = KVp + ((size_t)(is * 64 + bh)) * 4096;
#pragma unroll
    for (int i = 0; i < 4; ++i) {
        float4 o; o.x = acc[i][0]; o.y = acc[i][1]; o.z = acc[i][2]; o.w = acc[i][3];
        *(float4*)&outp[(d0 + i) * 64 + e0] = o;
    }
}

// ---------------------------------------------------------------------------
__global__ __launch_bounds__(256)
void reduce_kv8(const float4* __restrict__ in, float4* __restrict__ out)
{
    const int i = blockIdx.x * 256 + threadIdx.x;
    float4 a = in[i];
#pragma unroll
    for (int s = 1; s < 8; ++s) {
        const float4 b = in[s * 65536 + i];
        a.x += b.x; a.y += b.y; a.z += b.z; a.w += b.w;
    }
    out[i] = a;
}

// ---------------------------------------------------------------------------
// E_t[b][j][h*64+d] = scale * sum_e kv[b,h,d,e] * W_o[j, h*64+e]
// ---------------------------------------------------------------------------
__global__ __launch_bounds__(256)
void make_E(const float* __restrict__ KV, const float* __restrict__ Wo,
            ushort_t* __restrict__ Et)
{
    __shared__ float skv[64 * 65];
    __shared__ float swo[64 * 65];

    const int t  = threadIdx.x;
    const int bh = blockIdx.y;
    const int b  = bh >> 4, h = bh & 15;
    const int j0 = blockIdx.x * 64;

    const float* kvp = KV + (size_t)bh * 4096;
#pragma unroll
    for (int i = 0; i < 4; ++i) {
        const int idx = t + i * 256;
        const int r = idx >> 4, c = (idx & 15) * 4;
        const float4 f = *(const float4*)&kvp[r * 64 + c];
        skv[r * 65 + c + 0] = f.x;
        skv[r * 65 + c + 1] = f.y;
        skv[r * 65 + c + 2] = f.z;
        skv[r * 65 + c + 3] = f.w;
        const float4 g = *(const float4*)&Wo[(size_t)(j0 + r) * 1024 + h * 64 + c];
        swo[r * 65 + c + 0] = g.x;
        swo[r * 65 + c + 1] = g.y;
        swo[r * 65 + c + 2] = g.z;
        swo[r * 65 + c + 3] = g.w;
    }
    __syncthreads();

    const int d0 = (t & 15) * 4;
#pragma unroll
    for (int pass = 0; pass < 4; ++pass) {
        const int jloc = (t >> 4) + pass * 16;
        float s0 = 0.f, s1 = 0.f, s2 = 0.f, s3 = 0.f;
        const float* wrow = &swo[jloc * 65];
#pragma unroll 8
        for (int e = 0; e < 64; ++e) {
            const float w = wrow[e];
            s0 += skv[(d0 + 0) * 65 + e] * w;
            s1 += skv[(d0 + 1) * 65 + e] * w;
            s2 += skv[(d0 + 2) * 65 + e] * w;
            s3 += skv[(d0 + 3) * 65 + e] * w;
        }
        ushort4 o;
        o.x = f2bf(s0 * 0.125f);
        o.y = f2bf(s1 * 0.125f);
        o.z = f2bf(s2 * 0.125f);
        o.w = f2bf(s3 * 0.125f);
        *(ushort4*)&Et[((size_t)b * 1024 + j0 + jloc) * 1024 + h * 64 + d0] = o;
    }
}

// ---------------------------------------------------------------------------

extern "C" void kernel_launch(void* const* d_in, const int* in_sizes, int n_in,
                              void* d_out, int out_size, void* d_ws, size_t ws_size,
                              hipStream_t stream)
{
    const float* x  = (const float*)d_in[0];
    const float* Wq = (const float*)d_in[1];
    const float* Wk = (const float*)d_in[2];
    const float* Wv = (const float*)d_in[3];
    const float* Wo = (const float*)d_in[4];
    float* out = (float*)d_out;

    const int B = 4, S = 4096, D = 1024;
    const long MB1 = 1048576;

    char* ws = (char*)d_ws;
    size_t off = 0;
    auto alloc = [&](size_t bytes) -> void* {
        void* p = ws + off;
        off += (bytes + 255) & ~(size_t)255;
        return p;
    };
    ushort_t* xb   = (ushort_t*)alloc((size_t)B * S * D * 2);      // 33.5 MB
    ushort_t* xbT  = (ushort_t*)alloc((size_t)D * B * S * 2);      // 33.5 MB
    ushort_t* wkv  = (ushort_t*)alloc((size_t)2 * D * D * 2);      // wk | wv
    ushort_t* wqT  = (ushort_t*)alloc((size_t)D * D * 2);
    ushort_t* Gb   = (ushort_t*)alloc((size_t)B * D * D * 2);      // 8.4 MB
    float*    kvp  = (float*)alloc((size_t)8 * 64 * 4096 * 4);     // 8.4 MB
    float*    kvr  = (float*)alloc((size_t)64 * 4096 * 4);         // 1 MB
    ushort_t* Fb   = (ushort_t*)alloc((size_t)B * D * D * 2);      // 8.4 MB
    char*     R1   = (char*)alloc((size_t)16 * MB1 * 2);           // 33.5 MB shared
    ushort_t* Gp = (ushort_t*)R1;                    // [16][1M] bf16 partials
    ushort_t* Hb = (ushort_t*)R1;                    // [4][1M] (Gp[0..7] dead after reduce)
    ushort_t* Et = (ushort_t*)(R1 + 8 * MB1 * 2);    // [4][1M] (Gp[8..15] dead after reduce)
    ushort_t* wkb = wkv;
    ushort_t* wvb = wkv + MB1;

    // casts
    cast_x_t<<<dim3(256, 16), dim3(256), 0, stream>>>(x, xb, xbT);
    cast_w2<<<dim3(1024, 2), dim3(256), 0, stream>>>(Wk, Wv, wkv);
    cast_wt<<<dim3(16, 16), dim3(256), 0, stream>>>(Wq, wqT);

    // G[b] = x^T x, symmetric: 36 upper-triangle 128-tiles, split-K=4, z fastest
    gemm_gram<<<dim3(16, 36), dim3(256), 0, stream>>>(xbT, Gp);
    reduce_g_t<<<dim3(256, 4), dim3(256), 0, stream>>>(Gp, Gb);

    // H[b] = Wk @ G[b]  (G symmetric -> use as B directly); 512 blocks, 2/CU
    gemm_bt_n64<ushort_t><<<dim3(8, 16, 4), dim3(256), 0, stream>>>(
        wkb, D, 0, Gb, D, MB1, Hb, D, MB1, D);

    // kv[b,h] = H_h @ Wv_h^T (i-split 8) + reduce
    kvblk<<<dim3(8, 64), dim3(256), 0, stream>>>(Hb, wvb, kvp);
    reduce_kv8<<<dim3(256), dim3(256), 0, stream>>>((const float4*)kvp, (float4*)kvr);

    // E_t
    make_E<<<dim3(16, 64), dim3(256), 0, stream>>>(kvr, Wo, Et);

    // F[b] = E_t[b] @ Wq; 512 blocks, 2/CU
    gemm_bt_n64<ushort_t><<<dim3(8, 16, 4), dim3(256), 0, stream>>>(
        Et, D, MB1, wqT, D, 0, Fb, D, (long)D * D, D);

    // out[b] = x[b] @ F[b]^T -> fp32: 256x128 3-buf, split-lgkm + XCD swizzle
    gemm_fin<<<dim3(16, 8, 4), dim3(256), 0, stream>>>(
        xb, D, (long)S * D, Fb, D, (long)D * D, out, D, (long)S * D, D);
}

// Round 6
// 308.321 us; speedup vs baseline: 1.0226x; 1.0226x over previous
//
#include <hip/hip_runtime.h>
#include <hip/hip_bf16.h>
#include <cstdint>

// ---------------------------------------------------------------------------
// LinearMultiHeadAttention: B=4, S=4096, D_MODEL=1024, H=16, Dk=64
// Gram-path:
//   G[b]  = x[b]^T x[b]     (SYMMETRIC: upper-triangle tiles only, split-K=4)
//   H[b]  = Wk @ G[b]
//   kv[b,h] = H_h @ Wv_h^T
//   E_t[b][j][hd] = scale*sum_e kv*Wo
//   F[b]  = E_t[b] @ Wq
//   out   = x @ F[b]^T
// R12 vs R11: DISPATCH-COUNT reduction (wall ~315us vs ~160us kernel-sum ->
// ~150us of inter-dispatch gaps across 10 boundaries):
//   - prep: cast_x_t + Wk/Wv casts + Wq transpose in ONE kernel (role by
//     blockIdx). 3 dispatches -> 1.
//   - make_E8: sums the 8 kvblk partials during LDS staging -> reduce_kv8
//     deleted. 2 dispatches -> 1.
//   - gemm_fin: R10 body (single lgkmcnt(0); split-lgkm cost +2us in R11)
//     + R11 XCD-bijective remap (proven FETCH 49.4->42.6MB). Ledger as R10.
//   Pipeline: prep, gram, reduce_g, H, kvblk, make_E8, F, fin = 8 dispatches.
// ---------------------------------------------------------------------------

typedef __bf16 bf16x8 __attribute__((ext_vector_type(8)));
typedef float f32x4 __attribute__((ext_vector_type(4)));
typedef unsigned short ushort_t;

__device__ inline void gld_lds16(const void* g, void* l) {
    __builtin_amdgcn_global_load_lds(
        (const __attribute__((address_space(1))) unsigned int*)g,
        (__attribute__((address_space(3))) unsigned int*)l,
        16, 0, 0);
}

__device__ inline ushort_t f2bf(float f) {
    uint32_t u = __float_as_uint(f);
    uint32_t r = (u + 0x7fffu + ((u >> 16) & 1u)) >> 16;
    return (ushort_t)r;
}
__device__ inline float bf2f(ushort_t u) {
    return __uint_as_float((uint32_t)u << 16);
}

// ---------------------------------------------------------------------------
// prep: one kernel, three roles by blockIdx.x:
//   [0,4096)    cast x fp32 -> xb bf16 + xbT bf16 (64x64 LDS transpose tile)
//   [4096,5120) plain cast Wk|Wv -> wkv (2048 floats per block)
//   [5120,5376) cast+transpose Wq -> wqT (64x64 tile)
// ---------------------------------------------------------------------------
__global__ __launch_bounds__(256)
void prep(const float* __restrict__ x, const float* __restrict__ Wk,
          const float* __restrict__ Wv, const float* __restrict__ Wq,
          ushort_t* __restrict__ xb, ushort_t* __restrict__ xbT,
          ushort_t* __restrict__ wkv, ushort_t* __restrict__ wqT)
{
    __shared__ ushort_t lt[64 * 66];
    const int id = blockIdx.x;
    const int t  = threadIdx.x;

    if (id < 4096) {
        // ---- cast_x role ----
        const int s0 = (id & 255) * 64;
        const int i0 = (id >> 8) * 64;
#pragma unroll
        for (int c = 0; c < 4; ++c) {
            const int idx = c * 256 + t;
            const int r = idx >> 4, c4 = (idx & 15) * 4;
            const float4 f = *(const float4*)&x[(size_t)(s0 + r) * 1024 + i0 + c4];
            ushort4 o;
            o.x = f2bf(f.x); o.y = f2bf(f.y); o.z = f2bf(f.z); o.w = f2bf(f.w);
            *(ushort4*)&xb[(size_t)(s0 + r) * 1024 + i0 + c4] = o;
            *(uint32_t*)&lt[r * 66 + c4]     = (uint32_t)o.x | ((uint32_t)o.y << 16);
            *(uint32_t*)&lt[r * 66 + c4 + 2] = (uint32_t)o.z | ((uint32_t)o.w << 16);
        }
        __syncthreads();
#pragma unroll
        for (int c = 0; c < 4; ++c) {
            const int idx = c * 256 + t;
            const int ri = idx >> 4, s4 = (idx & 15) * 4;
            ushort4 o;
            o.x = lt[(s4 + 0) * 66 + ri];
            o.y = lt[(s4 + 1) * 66 + ri];
            o.z = lt[(s4 + 2) * 66 + ri];
            o.w = lt[(s4 + 3) * 66 + ri];
            *(ushort4*)&xbT[(size_t)(i0 + ri) * 16384 + s0 + s4] = o;
        }
        return;
    }

    if (id < 5120) {
        // ---- Wk/Wv plain cast: block q covers 2048 floats (1M boundary is
        // 2048-aligned so a block never straddles Wk|Wv) ----
        const int q  = id - 4096;                 // 0..1023
        const int qq = (q < 512) ? q : q - 512;
        const float* src = (q < 512) ? Wk : Wv;
        const float* s = src + (size_t)qq * 2048 + t * 8;
        ushort_t* d = wkv + (size_t)q * 2048 + t * 8;
        const float4 f0 = *(const float4*)(s);
        const float4 f1 = *(const float4*)(s + 4);
        ushort4 o0, o1;
        o0.x = f2bf(f0.x); o0.y = f2bf(f0.y); o0.z = f2bf(f0.z); o0.w = f2bf(f0.w);
        o1.x = f2bf(f1.x); o1.y = f2bf(f1.y); o1.z = f2bf(f1.z); o1.w = f2bf(f1.w);
        *(ushort4*)(d)     = o0;
        *(ushort4*)(d + 4) = o1;
        return;
    }

    // ---- Wq transpose role ----
    const int id2 = id - 5120;                    // 0..255
    const int r0 = (id2 >> 4) * 64;
    const int c0 = (id2 & 15) * 64;
#pragma unroll
    for (int c = 0; c < 4; ++c) {
        const int idx = c * 256 + t;
        const int r = idx >> 4, c4 = (idx & 15) * 4;
        const float4 f = *(const float4*)&Wq[(size_t)(r0 + r) * 1024 + c0 + c4];
        ushort4 o;
        o.x = f2bf(f.x); o.y = f2bf(f.y); o.z = f2bf(f.z); o.w = f2bf(f.w);
        *(uint32_t*)&lt[r * 66 + c4]     = (uint32_t)o.x | ((uint32_t)o.y << 16);
        *(uint32_t*)&lt[r * 66 + c4 + 2] = (uint32_t)o.z | ((uint32_t)o.w << 16);
    }
    __syncthreads();
#pragma unroll
    for (int c = 0; c < 4; ++c) {
        const int idx = c * 256 + t;
        const int ri = idx >> 4, s4 = (idx & 15) * 4;
        ushort4 o;
        o.x = lt[(s4 + 0) * 66 + ri];
        o.y = lt[(s4 + 1) * 66 + ri];
        o.z = lt[(s4 + 2) * 66 + ri];
        o.w = lt[(s4 + 3) * 66 + ri];
        *(ushort4*)&wqT[(size_t)(c0 + ri) * 1024 + r0 + s4] = o;
    }
}

// ---------------------------------------------------------------------------
// C = A @ B^T. 128x64 tile, BK=32, XOR-swizzled LDS. 256 thr = 4 waves (2Mx2N),
// per-wave 64x32 out. 512 blocks for 1024x1024 GEMMs -> 2/CU resident.
// ---------------------------------------------------------------------------
template <typename OutT>
__global__ __launch_bounds__(256, 4)
void gemm_bt_n64(const ushort_t* __restrict__ A, int lda, long strideA,
                 const ushort_t* __restrict__ B, int ldb, long strideB,
                 OutT* __restrict__ C0, int ldc0, long strideC0, int K)
{
    __shared__ ushort_t lA[128 * 32];
    __shared__ ushort_t lB[64 * 32];

    const int t    = threadIdx.x;
    const int lane = t & 63;
    const int wid  = t >> 6;          // 0..3
    const int z    = blockIdx.z;

    A += (size_t)z * strideA;
    B += (size_t)z * strideB;

    const int m0 = blockIdx.x * 128;
    const int n0 = blockIdx.y * 64;

    const int wm = (wid >> 1) * 64;   // 0,64
    const int wn = (wid & 1) * 32;    // 0,32
    const int mr = lane & 15;
    const int q4 = lane >> 4;

    const int row_a = t >> 2;                       // 0..63
    const int seg   = ((t & 3) ^ ((t >> 3) & 3)) * 8;
    const int csw   = (q4 ^ ((mr >> 1) & 3)) * 16;

    f32x4 acc[4][2] = {};

    for (int k0 = 0; k0 < K; k0 += 32) {
        __syncthreads();
        gld_lds16(A + (size_t)(m0 + row_a) * lda + k0 + seg,      (char*)lA + wid * 1024);
        gld_lds16(A + (size_t)(m0 + 64 + row_a) * lda + k0 + seg, (char*)lA + 4096 + wid * 1024);
        gld_lds16(B + (size_t)(n0 + row_a) * ldb + k0 + seg,      (char*)lB + wid * 1024);
        __syncthreads();

        bf16x8 af[4], bf[2];
#pragma unroll
        for (int i = 0; i < 4; ++i)
            af[i] = *(const bf16x8*)((const char*)lA + (wm + i * 16 + mr) * 64 + csw);
#pragma unroll
        for (int j = 0; j < 2; ++j)
            bf[j] = *(const bf16x8*)((const char*)lB + (wn + j * 16 + mr) * 64 + csw);
#pragma unroll
        for (int i = 0; i < 4; ++i)
#pragma unroll
            for (int j = 0; j < 2; ++j)
                acc[i][j] = __builtin_amdgcn_mfma_f32_16x16x32_bf16(af[i], bf[j], acc[i][j], 0, 0, 0);
    }

    OutT* Cw = C0 + (size_t)z * strideC0;
#pragma unroll
    for (int i = 0; i < 4; ++i) {
        const int rbase = m0 + wm + i * 16 + q4 * 4;
#pragma unroll
        for (int j = 0; j < 2; ++j) {
            const int col = n0 + wn + j * 16 + mr;
#pragma unroll
            for (int r = 0; r < 4; ++r) {
                const float v = acc[i][j][r];
                const size_t off = (size_t)(rbase + r) * ldc0 + col;
                if constexpr (sizeof(OutT) == 2) Cw[off] = f2bf(v);
                else                             Cw[off] = v;
            }
        }
    }
}

// ---------------------------------------------------------------------------
// FINAL GEMM: C = A @ B^T fp32. 256x128 tile, BK=32, 4 waves, wave = 128x64
// (acc[8][4], 32 MFMA / 12 ds_read). TRIPLE-buffered LDS (3x24KB=72KB) ->
// 2 blocks/CU. One s_barrier per kt, counted-vmcnt ledger:
//   prologue stage(0),stage(1), vmcnt(6), BAR.
//   iter kt: rd 12 frags from buf[cur] | stage(kt+2)->buf[cur+2] | lgkm0 |
//            32 MFMA | vmcnt(6) (drain kt+1, leave kt+2) | BAR.
// R12: R10 body (single lgkm0) + R11 XCD-bijective remap (FETCH -14%).
// ---------------------------------------------------------------------------
__global__ __launch_bounds__(256, 2)
void gemm_fin(const ushort_t* __restrict__ A, int lda, long strideA,
              const ushort_t* __restrict__ B, int ldb, long strideB,
              float* __restrict__ C, int ldc, long strideC, int K)
{
    __shared__ char lds[73728];      // 3 x 24576 (A@0..16K, B@16K..24K)

    const int t    = threadIdx.x;    // 256
    const int lane = t & 63;
    const int wid  = t >> 6;         // 0..3

    // XCD-bijective remap: 512 blocks = 8 XCD chunks of 64. Chunk c (= XCD)
    // covers z = c/2, by in {4(c&1)..4(c&1)+3}, all bx -> B panels and the
    // z-slice XCD-L2-resident; A panels reused 8x within chunk.
    const int L  = blockIdx.x + (blockIdx.y << 4) + (blockIdx.z << 7);
    const int w  = ((L & 7) << 6) + (L >> 3);
    const int bx = w & 15, by = (w >> 4) & 7, z = w >> 7;

    A += (size_t)z * strideA;
    B += (size_t)z * strideB;

    const int m0 = bx * 256;
    const int n0 = by * 128;

    const int wr = wid >> 1;         // 0..1: 128-row half of A-tile
    const int wn = wid & 1;          // 0..1: 64-col half of B-tile
    const int mr = lane & 15;
    const int q4 = lane >> 4;

    const int NT = K >> 5;           // 32

    const int row_a = t >> 2;                         // 0..63
    const int seg   = ((t & 3) ^ ((t >> 3) & 3)) * 8; // inverse-swizzled src col
    const int csw   = (q4 ^ ((mr >> 1) & 3)) * 16;    // swizzled read col

    auto stage = [&](int tgt, int bsel) {
        if (tgt >= NT) return;
        char* base = lds + bsel * 24576 + wid * 1024;
        const ushort_t* gA = A + (size_t)(m0 + row_a) * lda + tgt * 32 + seg;
        gld_lds16(gA,                          base);          // rows   0..63
        gld_lds16(gA + ((size_t)lda << 6),     base + 4096);   // rows  64..127
        gld_lds16(gA + ((size_t)lda << 7),     base + 8192);   // rows 128..191
        gld_lds16(gA + (size_t)lda * 192,      base + 12288);  // rows 192..255
        const ushort_t* gB = B + (size_t)(n0 + row_a) * ldb + tgt * 32 + seg;
        gld_lds16(gB,                          base + 16384);  // rows   0..63
        gld_lds16(gB + ((size_t)ldb << 6),     base + 20480);  // rows  64..127
    };

    bf16x8 af[8], bf[4];
    f32x4 acc[8][4] = {};

    // prologue
    stage(0, 0);
    stage(1, 1);
    asm volatile("s_waitcnt vmcnt(6)" ::: "memory");
    __builtin_amdgcn_s_barrier();

    int cur = 0;
    for (int kt = 0; kt < NT; ++kt) {
        const char* buf = lds + cur * 24576;
#pragma unroll
        for (int i = 0; i < 8; ++i)
            af[i] = *(const bf16x8*)(buf + (wr * 128 + i * 16 + mr) * 64 + csw);
#pragma unroll
        for (int j = 0; j < 4; ++j)
            bf[j] = *(const bf16x8*)(buf + 16384 + (wn * 64 + j * 16 + mr) * 64 + csw);

        int b2 = cur + 2; if (b2 >= 3) b2 -= 3;
        stage(kt + 2, b2);

        asm volatile("s_waitcnt lgkmcnt(0)" ::: "memory");
        __builtin_amdgcn_sched_barrier(0);
        __builtin_amdgcn_s_setprio(1);
#pragma unroll
        for (int i = 0; i < 8; ++i)
#pragma unroll
            for (int j = 0; j < 4; ++j)
                acc[i][j] = __builtin_amdgcn_mfma_f32_16x16x32_bf16(
                    af[i], bf[j], acc[i][j], 0, 0, 0);
        __builtin_amdgcn_s_setprio(0);
        __builtin_amdgcn_sched_barrier(0);

        if (kt + 2 < NT)       asm volatile("s_waitcnt vmcnt(6)" ::: "memory");
        else if (kt + 2 == NT) asm volatile("s_waitcnt vmcnt(0)" ::: "memory");
        __builtin_amdgcn_s_barrier();
        if (++cur == 3) cur = 0;
    }

    float* Cw = C + (size_t)z * strideC;
#pragma unroll
    for (int i = 0; i < 8; ++i) {
        const int rbase = m0 + wr * 128 + i * 16 + q4 * 4;
#pragma unroll
        for (int j = 0; j < 4; ++j) {
            const int col = n0 + wn * 64 + j * 16 + mr;
#pragma unroll
            for (int r = 0; r < 4; ++r)
                Cw[(size_t)(rbase + r) * ldc + col] = acc[i][j][r];
        }
    }
}

// ---------------------------------------------------------------------------
// Gram GEMM: Gp[z] partial of x[b]^T x[b], upper-triangle 128-tiles only.
// grid (16 z fastest -> XCD round-robin, 36 triangle tiles). A = B = xbT.
// z = b*4+ks: columns b*4096 + ks*1024 of xbT [1024][16384].
// ---------------------------------------------------------------------------
__global__ __launch_bounds__(256, 2)
void gemm_gram(const ushort_t* __restrict__ X, ushort_t* __restrict__ Gp)
{
    __shared__ ushort_t lA[128 * 32];
    __shared__ ushort_t lB[128 * 32];

    const int t    = threadIdx.x;
    const int lane = t & 63;
    const int wid  = t >> 6;

    const int z  = blockIdx.x;
    const int bb = z >> 2, ks = z & 3;

    // triangle tile map: row ti has 8-ti tiles (ti<=tj)
    int ti = 0, rem = blockIdx.y;
    while (rem >= 8 - ti) { rem -= 8 - ti; ++ti; }
    const int tj = ti + rem;
    const int m0 = ti * 128;
    const int n0 = tj * 128;

    const ushort_t* A = X + (size_t)bb * 4096 + (size_t)ks * 1024;

    const int wm = (wid >> 1) * 64;
    const int wn = (wid & 1) * 64;
    const int mr = lane & 15;
    const int q4 = lane >> 4;

    const int row_a = t >> 2;
    const int seg   = ((t & 3) ^ ((t >> 3) & 3)) * 8;
    const int csw   = (q4 ^ ((mr >> 1) & 3)) * 16;

    f32x4 acc[4][4] = {};

    for (int k0 = 0; k0 < 1024; k0 += 32) {
        __syncthreads();
        gld_lds16(A + (size_t)(m0 + row_a) * 16384 + k0 + seg,      (char*)lA + wid * 1024);
        gld_lds16(A + (size_t)(m0 + 64 + row_a) * 16384 + k0 + seg, (char*)lA + 4096 + wid * 1024);
        gld_lds16(A + (size_t)(n0 + row_a) * 16384 + k0 + seg,      (char*)lB + wid * 1024);
        gld_lds16(A + (size_t)(n0 + 64 + row_a) * 16384 + k0 + seg, (char*)lB + 4096 + wid * 1024);
        __syncthreads();

        bf16x8 af[4], bf[4];
#pragma unroll
        for (int i = 0; i < 4; ++i)
            af[i] = *(const bf16x8*)((const char*)lA + (wm + i * 16 + mr) * 64 + csw);
#pragma unroll
        for (int j = 0; j < 4; ++j)
            bf[j] = *(const bf16x8*)((const char*)lB + (wn + j * 16 + mr) * 64 + csw);
#pragma unroll
        for (int i = 0; i < 4; ++i)
#pragma unroll
            for (int j = 0; j < 4; ++j)
                acc[i][j] = __builtin_amdgcn_mfma_f32_16x16x32_bf16(af[i], bf[j], acc[i][j], 0, 0, 0);
    }

    ushort_t* Cw = Gp + ((size_t)z << 20);
#pragma unroll
    for (int i = 0; i < 4; ++i) {
        const int rbase = m0 + wm + i * 16 + q4 * 4;
#pragma unroll
        for (int j = 0; j < 4; ++j) {
            const int col = n0 + wn + j * 16 + mr;
#pragma unroll
            for (int r = 0; r < 4; ++r)
                Cw[(size_t)(rbase + r) * 1024 + col] = f2bf(acc[i][j][r]);
        }
    }
}

// ---------------------------------------------------------------------------
// reduce_g_t: G[b][tr*64+r][tc*64+c] = sum_ks Gp[b*4+ks] at source 64-tile
// (sr,sc)=(min,max). Lower tiles transpose through LDS (pitch 65).
// ---------------------------------------------------------------------------
__global__ __launch_bounds__(256)
void reduce_g_t(const ushort_t* __restrict__ Gp, ushort_t* __restrict__ G)
{
    __shared__ float acc[64 * 65];

    const int t  = threadIdx.x;
    const int b  = blockIdx.y;
    const int tr = blockIdx.x >> 4, tc = blockIdx.x & 15;
    const int sr = (tr <= tc) ? tr : tc;
    const int sc = (tr <= tc) ? tc : tr;
    const bool flip = tr > tc;

#pragma unroll
    for (int p = 0; p < 4; ++p) {
        const int idx = p * 256 + t;
        const int r = idx >> 4, c = (idx & 15) * 4;
        float a0 = 0.f, a1 = 0.f, a2 = 0.f, a3 = 0.f;
#pragma unroll
        for (int ksl = 0; ksl < 4; ++ksl) {
            const ushort4 u = *(const ushort4*)&Gp[((size_t)(b * 4 + ksl) << 20)
                                                   + (size_t)(sr * 64 + r) * 1024 + sc * 64 + c];
            a0 += bf2f(u.x); a1 += bf2f(u.y); a2 += bf2f(u.z); a3 += bf2f(u.w);
        }
        acc[r * 65 + c + 0] = a0;
        acc[r * 65 + c + 1] = a1;
        acc[r * 65 + c + 2] = a2;
        acc[r * 65 + c + 3] = a3;
    }
    __syncthreads();

#pragma unroll
    for (int p = 0; p < 4; ++p) {
        const int idx = p * 256 + t;
        const int r = idx >> 4, c = (idx & 15) * 4;
        float v0, v1, v2, v3;
        if (flip) {
            v0 = acc[(c + 0) * 65 + r];
            v1 = acc[(c + 1) * 65 + r];
            v2 = acc[(c + 2) * 65 + r];
            v3 = acc[(c + 3) * 65 + r];
        } else {
            v0 = acc[r * 65 + c + 0];
            v1 = acc[r * 65 + c + 1];
            v2 = acc[r * 65 + c + 2];
            v3 = acc[r * 65 + c + 3];
        }
        ushort4 o;
        o.x = f2bf(v0); o.y = f2bf(v1); o.z = f2bf(v2); o.w = f2bf(v3);
        *(ushort4*)&G[((size_t)b << 20) + (size_t)(tr * 64 + r) * 1024 + tc * 64 + c] = o;
    }
}

// ---------------------------------------------------------------------------
// kv partials: KVp[is][bh][d][e] = sum_{i-slice} H[b][h64+d][i]*Wv[h64+e][i]
// ---------------------------------------------------------------------------
__global__ __launch_bounds__(256)
void kvblk(const ushort_t* __restrict__ H, const ushort_t* __restrict__ Wv,
           float* __restrict__ KVp)
{
    __shared__ ushort_t sH[64 * 132];
    __shared__ ushort_t sV[64 * 132];

    const int t  = threadIdx.x;
    const int is = blockIdx.x;
    const int bh = blockIdx.y;
    const int b  = bh >> 4, h = bh & 15;

    const ushort_t* Hp = H + ((size_t)b << 20) + (size_t)(h * 64) * 1024 + is * 128;
    const ushort_t* Vp = Wv + (size_t)(h * 64) * 1024 + is * 128;

#pragma unroll
    for (int i2 = 0; i2 < 8; ++i2) {
        const int ci = i2 * 256 + t;
        const int r = ci >> 5, c = (ci & 31) * 4;
        *(uint2*)&sH[r * 132 + c] = *(const uint2*)&Hp[(size_t)r * 1024 + c];
        *(uint2*)&sV[r * 132 + c] = *(const uint2*)&Vp[(size_t)r * 1024 + c];
    }
    __syncthreads();

    const int d0 = (t >> 4) * 4;
    const int e0 = (t & 15) * 4;
    float acc[4][4] = {};

#pragma unroll 2
    for (int i4 = 0; i4 < 128; i4 += 4) {
        uint2 hu[4], vu[4];
#pragma unroll
        for (int j = 0; j < 4; ++j) {
            hu[j] = *(const uint2*)&sH[(d0 + j) * 132 + i4];
            vu[j] = *(const uint2*)&sV[(e0 + j) * 132 + i4];
        }
        float hf[4][4], vf[4][4];
#pragma unroll
        for (int j = 0; j < 4; ++j) {
            hf[j][0] = __uint_as_float(hu[j].x << 16);
            hf[j][1] = __uint_as_float(hu[j].x & 0xffff0000u);
            hf[j][2] = __uint_as_float(hu[j].y << 16);
            hf[j][3] = __uint_as_float(hu[j].y & 0xffff0000u);
            vf[j][0] = __uint_as_float(vu[j].x << 16);
            vf[j][1] = __uint_as_float(vu[j].x & 0xffff0000u);
            vf[j][2] = __uint_as_float(vu[j].y << 16);
            vf[j][3] = __uint_as_float(vu[j].y & 0xffff0000u);
        }
#pragma unroll
        for (int ii = 0; ii < 4; ++ii)
#pragma unroll
            for (int di = 0; di < 4; ++di)
#pragma unroll
                for (int ej = 0; ej < 4; ++ej)
                    acc[di][ej] += hf[di][ii] * vf[ej][ii];
    }

    float* outp = KVp + ((size_t)(is * 64 + bh)) * 4096;
#pragma unroll
    for (int i = 0; i < 4; ++i) {
        float4 o; o.x = acc[i][0]; o.y = acc[i][1]; o.z = acc[i][2]; o.w = acc[i][3];
        *(float4*)&outp[(d0 + i) * 64 + e0] = o;
    }
}

// ---------------------------------------------------------------------------
// make_E8: E_t[b][j][h*64+d] = scale * sum_e kv[b,h,d,e] * W_o[j, h*64+e]
// kv summed from the 8 kvblk partials during staging (reduce_kv8 deleted).
// ---------------------------------------------------------------------------
__global__ __launch_bounds__(256)
void make_E8(const float* __restrict__ KVp, const float* __restrict__ Wo,
             ushort_t* __restrict__ Et)
{
    __shared__ float skv[64 * 65];
    __shared__ float swo[64 * 65];

    const int t  = threadIdx.x;
    const int bh = blockIdx.y;
    const int b  = bh >> 4, h = bh & 15;
    const int j0 = blockIdx.x * 64;

#pragma unroll
    for (int i = 0; i < 4; ++i) {
        const int idx = t + i * 256;
        const int r = idx >> 4, c = (idx & 15) * 4;
        float4 f; f.x = 0.f; f.y = 0.f; f.z = 0.f; f.w = 0.f;
#pragma unroll
        for (int is = 0; is < 8; ++is) {
            const float4 p = *(const float4*)&KVp[((size_t)(is * 64 + bh)) * 4096
                                                  + r * 64 + c];
            f.x += p.x; f.y += p.y; f.z += p.z; f.w += p.w;
        }
        skv[r * 65 + c + 0] = f.x;
        skv[r * 65 + c + 1] = f.y;
        skv[r * 65 + c + 2] = f.z;
        skv[r * 65 + c + 3] = f.w;
        const float4 g = *(const float4*)&Wo[(size_t)(j0 + r) * 1024 + h * 64 + c];
        swo[r * 65 + c + 0] = g.x;
        swo[r * 65 + c + 1] = g.y;
        swo[r * 65 + c + 2] = g.z;
        swo[r * 65 + c + 3] = g.w;
    }
    __syncthreads();

    const int d0 = (t & 15) * 4;
#pragma unroll
    for (int pass = 0; pass < 4; ++pass) {
        const int jloc = (t >> 4) + pass * 16;
        float s0 = 0.f, s1 = 0.f, s2 = 0.f, s3 = 0.f;
        const float* wrow = &swo[jloc * 65];
#pragma unroll 8
        for (int e = 0; e < 64; ++e) {
            const float w = wrow[e];
            s0 += skv[(d0 + 0) * 65 + e] * w;
            s1 += skv[(d0 + 1) * 65 + e] * w;
            s2 += skv[(d0 + 2) * 65 + e] * w;
            s3 += skv[(d0 + 3) * 65 + e] * w;
        }
        ushort4 o;
        o.x = f2bf(s0 * 0.125f);
        o.y = f2bf(s1 * 0.125f);
        o.z = f2bf(s2 * 0.125f);
        o.w = f2bf(s3 * 0.125f);
        *(ushort4*)&Et[((size_t)b * 1024 + j0 + jloc) * 1024 + h * 64 + d0] = o;
    }
}

// ---------------------------------------------------------------------------

extern "C" void kernel_launch(void* const* d_in, const int* in_sizes, int n_in,
                              void* d_out, int out_size, void* d_ws, size_t ws_size,
                              hipStream_t stream)
{
    const float* x  = (const float*)d_in[0];
    const float* Wq = (const float*)d_in[1];
    const float* Wk = (const float*)d_in[2];
    const float* Wv = (const float*)d_in[3];
    const float* Wo = (const float*)d_in[4];
    float* out = (float*)d_out;

    const int B = 4, S = 4096, D = 1024;
    const long MB1 = 1048576;

    char* ws = (char*)d_ws;
    size_t off = 0;
    auto alloc = [&](size_t bytes) -> void* {
        void* p = ws + off;
        off += (bytes + 255) & ~(size_t)255;
        return p;
    };
    ushort_t* xb   = (ushort_t*)alloc((size_t)B * S * D * 2);      // 33.5 MB
    ushort_t* xbT  = (ushort_t*)alloc((size_t)D * B * S * 2);      // 33.5 MB
    ushort_t* wkv  = (ushort_t*)alloc((size_t)2 * D * D * 2);      // wk | wv
    ushort_t* wqT  = (ushort_t*)alloc((size_t)D * D * 2);
    ushort_t* Gb   = (ushort_t*)alloc((size_t)B * D * D * 2);      // 8.4 MB
    float*    kvp  = (float*)alloc((size_t)8 * 64 * 4096 * 4);     // 8.4 MB
    ushort_t* Fb   = (ushort_t*)alloc((size_t)B * D * D * 2);      // 8.4 MB
    char*     R1   = (char*)alloc((size_t)16 * MB1 * 2);           // 33.5 MB shared
    ushort_t* Gp = (ushort_t*)R1;                    // [16][1M] bf16 partials
    ushort_t* Hb = (ushort_t*)R1;                    // [4][1M] (Gp[0..7] dead after reduce)
    ushort_t* Et = (ushort_t*)(R1 + 8 * MB1 * 2);    // [4][1M] (Gp[8..15] dead after reduce)
    ushort_t* wkb = wkv;
    ushort_t* wvb = wkv + MB1;

    // all input casts in one dispatch
    prep<<<dim3(5376), dim3(256), 0, stream>>>(x, Wk, Wv, Wq, xb, xbT, wkv, wqT);

    // G[b] = x^T x, symmetric: 36 upper-triangle 128-tiles, split-K=4, z fastest
    gemm_gram<<<dim3(16, 36), dim3(256), 0, stream>>>(xbT, Gp);
    reduce_g_t<<<dim3(256, 4), dim3(256), 0, stream>>>(Gp, Gb);

    // H[b] = Wk @ G[b]  (G symmetric -> use as B directly); 512 blocks, 2/CU
    gemm_bt_n64<ushort_t><<<dim3(8, 16, 4), dim3(256), 0, stream>>>(
        wkb, D, 0, Gb, D, MB1, Hb, D, MB1, D);

    // kv[b,h] = H_h @ Wv_h^T (i-split 8 partials)
    kvblk<<<dim3(8, 64), dim3(256), 0, stream>>>(Hb, wvb, kvp);

    // E_t (sums the 8 partials inline)
    make_E8<<<dim3(16, 64), dim3(256), 0, stream>>>(kvp, Wo, Et);

    // F[b] = E_t[b] @ Wq; 512 blocks, 2/CU
    gemm_bt_n64<ushort_t><<<dim3(8, 16, 4), dim3(256), 0, stream>>>(
        Et, D, MB1, wqT, D, 0, Fb, D, (long)D * D, D);

    // out[b] = x[b] @ F[b]^T -> fp32: 256x128 3-buf + XCD remap
    gemm_fin<<<dim3(16, 8, 4), dim3(256), 0, stream>>>(
        xb, D, (long)S * D, Fb, D, (long)D * D, out, D, (long)S * D, D);
}